// Round 1
// baseline (416.802 us; speedup 1.0000x reference)
//
#include <hip/hip_runtime.h>
#include <hip/hip_bf16.h>

// Problem constants
#define N_  4
#define C_  256
#define K_  16
#define T_  16
#define H_  56
#define W_  56
#define HW_ (H_ * W_)          // 3136
#define THW_ (T_ * HW_)        // 50176
#define TP_ 8
#define HP_ 28
#define WP_ 28
#define PP_ (HP_ * WP_)        // 784
#define CCHUNK 8

// ---------------------------------------------------------------------------
// Kernel 1: emap[n,t,h,w] = exp( max_k( sum_c w[n,k,c]*vw[n,c,t,h,w] ) / 16 )
// Each thread handles 2 consecutive spatial positions (float2 loads/stores).
// w[n] (16x256 f32 = 16KB) staged in LDS; read as float4 broadcast.
// ---------------------------------------------------------------------------
__global__ __launch_bounds__(256) void emap_kernel(const float* __restrict__ vw,
                                                   const float* __restrict__ w,
                                                   float* __restrict__ emap) {
    __shared__ float wl[K_ * C_];
    const int tid = threadIdx.x;
    const int bpn = THW_ / (256 * 2);      // 98 blocks per n
    const int n = blockIdx.x / bpn;
    const int lb = blockIdx.x % bpn;

    // stage w[n] into LDS
    const float* wn = w + n * (K_ * C_);
#pragma unroll
    for (int i = 0; i < K_; ++i) wl[i * C_ + tid] = wn[i * C_ + tid];
    __syncthreads();

    const int s = (lb * 256 + tid) * 2;    // spatial index within [0, THW_)
    const float* vbase = vw + (long)n * C_ * THW_ + s;

    float acc0[K_], acc1[K_];
#pragma unroll
    for (int k = 0; k < K_; ++k) { acc0[k] = 0.f; acc1[k] = 0.f; }

    for (int c4 = 0; c4 < C_; c4 += 4) {
        float2 v0 = *(const float2*)(vbase + (long)(c4 + 0) * THW_);
        float2 v1 = *(const float2*)(vbase + (long)(c4 + 1) * THW_);
        float2 v2 = *(const float2*)(vbase + (long)(c4 + 2) * THW_);
        float2 v3 = *(const float2*)(vbase + (long)(c4 + 3) * THW_);
#pragma unroll
        for (int k = 0; k < K_; ++k) {
            float4 wk = *(const float4*)&wl[k * C_ + c4];
            acc0[k] += wk.x * v0.x + wk.y * v1.x + wk.z * v2.x + wk.w * v3.x;
            acc1[k] += wk.x * v0.y + wk.y * v1.y + wk.z * v2.y + wk.w * v3.y;
        }
    }

    float m0 = acc0[0], m1 = acc1[0];
#pragma unroll
    for (int k = 1; k < K_; ++k) { m0 = fmaxf(m0, acc0[k]); m1 = fmaxf(m1, acc1[k]); }

    float2 e;
    e.x = expf(m0 * 0.0625f);
    e.y = expf(m1 * 0.0625f);
    *(float2*)(emap + (long)n * THW_ + s) = e;
}

// ---------------------------------------------------------------------------
// Kernel 2: box-sum (3x3x3, stride 2, pad 1) of vw*emap, divided by box-sum
// of emap. Block = (c-chunk, t', n). Stages the 3-slice emap window in LDS,
// computes reciprocal denominator tile once, then gathers vw per channel.
// ---------------------------------------------------------------------------
__global__ __launch_bounds__(256) void box_kernel(const float* __restrict__ vw,
                                                  const float* __restrict__ emap,
                                                  float* __restrict__ out) {
    __shared__ float se[3 * HW_];     // 37.6 KB: emap slices t0..t0+2 (zero pad)
    __shared__ float sden[PP_];       // 3.1 KB: reciprocal denominators

    const int tid = threadIdx.x;
    const int cb = blockIdx.x * CCHUNK;
    const int tp = blockIdx.y;
    const int n  = blockIdx.z;
    const int t0 = 2 * tp - 1;

    // stage emap window (t0, t0+1, t0+2); t0 == -1 only when tp == 0
    for (int sl = 0; sl < 3; ++sl) {
        const int tt = t0 + sl;
        if (tt >= 0) {
            const float* src = emap + (long)n * THW_ + (long)tt * HW_;
            for (int i = tid; i < HW_; i += 256) se[sl * HW_ + i] = src[i];
        } else {
            for (int i = tid; i < HW_; i += 256) se[sl * HW_ + i] = 0.f;
        }
    }
    __syncthreads();

    // denominator tile (shared across all channels)
    for (int p = tid; p < PP_; p += 256) {
        const int hp = p / WP_, wp = p % WP_;
        const int h0 = 2 * hp - 1, w0 = 2 * wp - 1;
        float ssum = 0.f;
#pragma unroll
        for (int dt = 0; dt < 3; ++dt) {
#pragma unroll
            for (int dh = 0; dh < 3; ++dh) {
                const int h = h0 + dh;
                if (h < 0) continue;          // h never >= 56
#pragma unroll
                for (int dw = 0; dw < 3; ++dw) {
                    const int w = w0 + dw;
                    if (w < 0) continue;      // w never >= 56
                    ssum += se[dt * HW_ + h * W_ + w];
                }
            }
        }
        sden[p] = 1.0f / ssum;
    }
    __syncthreads();

    // main: CCHUNK channels x 784 positions
    for (int idx = tid; idx < CCHUNK * PP_; idx += 256) {
        const int c = cb + idx / PP_;
        const int p = idx % PP_;
        const int hp = p / WP_, wp = p % WP_;
        const int h0 = 2 * hp - 1, w0 = 2 * wp - 1;
        const float* vbase = vw + ((long)n * C_ + c) * THW_;
        float num = 0.f;
#pragma unroll
        for (int dt = 0; dt < 3; ++dt) {
            const int tt = t0 + dt;
            if (tt < 0) continue;             // tt never >= 16
            const float* vt = vbase + (long)tt * HW_;
            const float* et = se + dt * HW_;
#pragma unroll
            for (int dh = 0; dh < 3; ++dh) {
                const int h = h0 + dh;
                if (h < 0) continue;
#pragma unroll
                for (int dw = 0; dw < 3; ++dw) {
                    const int w = w0 + dw;
                    if (w < 0) continue;
                    const int o = h * W_ + w;
                    num += vt[o] * et[o];
                }
            }
        }
        out[(((long)n * C_ + c) * TP_ + tp) * PP_ + p] = num * sden[p];
    }
}

extern "C" void kernel_launch(void* const* d_in, const int* in_sizes, int n_in,
                              void* d_out, int out_size, void* d_ws, size_t ws_size,
                              hipStream_t stream) {
    const float* vw = (const float*)d_in[0];
    const float* w  = (const float*)d_in[1];
    float* out  = (float*)d_out;
    float* emap = (float*)d_ws;     // needs N*T*H*W*4 = 802816 bytes

    // Kernel 1: 4 n * 98 blocks = 392 blocks
    emap_kernel<<<392, 256, 0, stream>>>(vw, w, emap);

    // Kernel 2: grid (c-chunks=32, t'=8, n=4) = 1024 blocks
    box_kernel<<<dim3(C_ / CCHUNK, TP_, N_), 256, 0, stream>>>(vw, emap, out);
}